// Round 14
// baseline (595.645 us; speedup 1.0000x reference)
//
#include <hip/hip_runtime.h>
#include <stdint.h>

// B=4, S=2048, D=1024, H=16, DEPTH=64
// out0: [B,S,D] f32 (8388608), out1: attn [B,H,S,S] f32 (268435456)

typedef float f32x4 __attribute__((ext_vector_type(4)));
typedef __bf16 bf16x8 __attribute__((ext_vector_type(8)));
typedef unsigned short u16x4 __attribute__((ext_vector_type(4)));
typedef unsigned short u16x8 __attribute__((ext_vector_type(8)));
typedef unsigned int u32x2 __attribute__((ext_vector_type(2)));

#define LOG2E 1.44269504088896340736f

static __device__ __forceinline__ f32x4 mfma16(bf16x8 a, bf16x8 b, f32x4 c) {
  return __builtin_amdgcn_mfma_f32_16x16x32_bf16(a, b, c, 0, 0, 0);
}
static __device__ __forceinline__ unsigned short bfc(float f) {
  return __builtin_bit_cast(unsigned short, (__bf16)f);
}
static __device__ __forceinline__ float e2(float x) { return __builtin_amdgcn_exp2f(x); }
static __device__ __forceinline__ float fb(unsigned int u) {
  return __builtin_bit_cast(float, u);
}
// Raw barrier draining ONLY LDS ops — nt global stores stay in flight across it.
// (R9/R12 lesson: __syncthreads drains vmcnt(0) and serializes the store pipeline.)
#define BAR_LGKM()                                            \
  do {                                                        \
    asm volatile("s_waitcnt lgkmcnt(0)" ::: "memory");        \
    __builtin_amdgcn_s_barrier();                             \
  } while (0)

#define GLDS16(g, l)                                                    \
  __builtin_amdgcn_global_load_lds(                                     \
      (const __attribute__((address_space(1))) void*)(g),               \
      (__attribute__((address_space(3))) void*)(l), 16, 0, 0)

struct Ptr3 { const float* s[3]; unsigned short* d[3]; };
struct Ptr4 { const float* s[4]; unsigned short* d[4]; };
struct QKArgs {
  const unsigned short* A[2];
  const unsigned short* Bt[2];
  const float* bias[2];
  unsigned short* C[2];
};

// ---------------- f32 -> bf16 conversion (all 3 inputs, z-indexed) ----------------
__global__ void cvt3(Ptr3 p) {
  const int z = blockIdx.z;
  const int i = (blockIdx.x * 256 + threadIdx.x) * 4;
  f32x4 v = *(const f32x4*)(const void*)(p.s[z] + i);
  u16x4 o;
  o[0] = bfc(v[0]); o[1] = bfc(v[1]); o[2] = bfc(v[2]); o[3] = bfc(v[3]);
  *(u16x4*)(void*)(p.d[z] + i) = o;
}

// ---------------- W [k][n] f32 -> Wt [n][k] bf16 (all 4, z-indexed) ----------------
__global__ void wtrans4(Ptr4 p) {
  __shared__ float t[32][33];
  const int z = blockIdx.z;
  const float* W = p.s[z];
  unsigned short* Wt = p.d[z];
  const int tx = threadIdx.x & 31, ty = threadIdx.x >> 5;
  const int n0 = blockIdx.x * 32, k0 = blockIdx.y * 32;
#pragma unroll
  for (int i = 0; i < 4; ++i)
    t[ty + i * 8][tx] = W[(size_t)(k0 + ty + i * 8) * 1024 + n0 + tx];
  __syncthreads();
#pragma unroll
  for (int i = 0; i < 4; ++i)
    Wt[(size_t)(n0 + ty + i * 8) * 1024 + k0 + tx] = bfc(t[tx][ty + i * 8]);
}

// ===== shared GEMM core (m97 structure: BK=32, single LDS buffer) =====
#define GEMM_PROLOG(Aptr, Btptr)                                        \
  __shared__ unsigned short sA[128 * 32];                               \
  __shared__ unsigned short sB[128 * 32];                               \
  const int tid = threadIdx.x;                                          \
  const int m0 = blockIdx.x << 7, n0 = blockIdx.y << 7;                 \
  const int w = tid >> 6, lane = tid & 63, g = lane >> 4, r = lane & 15;\
  const int wr = w >> 1, wc = w & 1;                                    \
  const int srow = tid >> 2;                                            \
  const int scol = (tid & 3) << 3;                                      \
  const unsigned short* ga = (Aptr) + (size_t)(m0 + srow) * 1024 + scol;\
  const unsigned short* gb = (Btptr) + (size_t)(n0 + srow) * 1024 + scol;\
  unsigned short* la = sA + tid * 8;                                    \
  unsigned short* lb = sB + tid * 8;

#define GEMM_KLOOP(SWAP)                                                \
  for (int kt = 0; kt < 32; ++kt) {                                     \
    const int ko = kt << 5;                                             \
    GLDS16(ga + ko, la);                                                \
    GLDS16(ga + ko + 64 * 1024, la + 64 * 32);                          \
    GLDS16(gb + ko, lb);                                                \
    GLDS16(gb + ko + 64 * 1024, lb + 64 * 32);                          \
    __syncthreads();                                                    \
    bf16x8 af[4], bfv[4];                                               \
    _Pragma("unroll")                                                   \
    for (int i = 0; i < 4; ++i) {                                       \
      af[i]  = *(const bf16x8*)(const void*)&sA[(wr * 64 + i * 16 + r) * 32 + g * 8]; \
      bfv[i] = *(const bf16x8*)(const void*)&sB[(wc * 64 + i * 16 + r) * 32 + g * 8]; \
    }                                                                   \
    _Pragma("unroll")                                                   \
    for (int i = 0; i < 4; ++i)                                         \
      _Pragma("unroll")                                                 \
      for (int j = 0; j < 4; ++j)                                       \
        acc[i][j] = (SWAP) ? mfma16(bfv[j], af[i], acc[i][j])           \
                           : mfma16(af[i], bfv[j], acc[i][j]);          \
    __syncthreads();                                                    \
  }

// ---------------- Q/K GEMM (z=0: Q pre-scaled by 0.125*log2e, z=1: K) ----------------
__global__ __launch_bounds__(256, 2) void gemm_qk(QKArgs args) {
  const int z = blockIdx.z;
  const f32x4 fz = {0.f, 0.f, 0.f, 0.f};
  f32x4 acc[4][4];
#pragma unroll
  for (int i = 0; i < 4; ++i)
#pragma unroll
    for (int j = 0; j < 4; ++j) acc[i][j] = fz;
  GEMM_PROLOG(args.A[z], args.Bt[z])
  GEMM_KLOOP(1)  // acc[i][j]: regs->n (j*16+g*4+t), lane r->m (i*16+r)
  const float osc = (z == 0) ? (0.125f * LOG2E) : 1.0f;
  unsigned short* Cq = args.C[z];
  const float* bias = args.bias[z];
#pragma unroll
  for (int j = 0; j < 4; ++j) {
    const int nb = n0 + wc * 64 + j * 16 + g * 4;
    const f32x4 b4 = *(const f32x4*)(const void*)(bias + nb);
#pragma unroll
    for (int i = 0; i < 4; ++i) {
      const int m = m0 + wr * 64 + i * 16 + r;
      const int bb = m >> 11, s = m & 2047, hh = nb >> 6, d = nb & 63;
      u16x4 pk;
#pragma unroll
      for (int t = 0; t < 4; ++t) pk[t] = bfc((acc[i][j][t] + b4[t]) * osc);
      *(u16x4*)(void*)(Cq + (size_t)(bb * 16 + hh) * 131072 + (size_t)s * 64 + d) = pk;
    }
  }
}

// ---------------- V GEMM -> transposed per-head [bh][d][s] ----------------
__global__ __launch_bounds__(256, 2) void gemm_v(const unsigned short* __restrict__ A,
                                                 const unsigned short* __restrict__ Bt,
                                                 const float* __restrict__ bias,
                                                 unsigned short* __restrict__ C) {
  const f32x4 fz = {0.f, 0.f, 0.f, 0.f};
  f32x4 acc[4][4];
#pragma unroll
  for (int i = 0; i < 4; ++i)
#pragma unroll
    for (int j = 0; j < 4; ++j) acc[i][j] = fz;
  GEMM_PROLOG(A, Bt)
  GEMM_KLOOP(0)  // acc[i][j]: regs->m (i*16+g*4+t), lane r->n (j*16+r)
#pragma unroll
  for (int j = 0; j < 4; ++j) {
    const int n = n0 + wc * 64 + j * 16 + r;
    const float bv = bias[n];
    const int hh = n >> 6, d = n & 63;
#pragma unroll
    for (int i = 0; i < 4; ++i) {
      const int m = m0 + wr * 64 + i * 16 + g * 4;
      const int bb = m >> 11, s = m & 2047;
      u16x4 pk;
#pragma unroll
      for (int t = 0; t < 4; ++t) pk[t] = bfc(acc[i][j][t] + bv);
      *(u16x4*)(void*)(C + (size_t)(bb * 16 + hh) * 131072 + (size_t)d * 2048 + s) = pk;
    }
  }
}

// ---------------- output GEMM: f32 [m][n], swapped, 16B stores ----------------
__global__ __launch_bounds__(256, 2) void gemm_o(const unsigned short* __restrict__ A,
                                                 const unsigned short* __restrict__ Bt,
                                                 const float* __restrict__ bias,
                                                 float* __restrict__ C) {
  const f32x4 fz = {0.f, 0.f, 0.f, 0.f};
  f32x4 acc[4][4];
#pragma unroll
  for (int i = 0; i < 4; ++i)
#pragma unroll
    for (int j = 0; j < 4; ++j) acc[i][j] = fz;
  GEMM_PROLOG(A, Bt)
  GEMM_KLOOP(1)
#pragma unroll
  for (int j = 0; j < 4; ++j) {
    const int nb = n0 + wc * 64 + j * 16 + g * 4;
    const f32x4 b4 = *(const f32x4*)(const void*)(bias + nb);
#pragma unroll
    for (int i = 0; i < 4; ++i) {
      const int m = m0 + wr * 64 + i * 16 + r;
      f32x4 c;
#pragma unroll
      for (int t = 0; t < 4; ++t) c[t] = acc[i][j][t] + b4[t];
      *(f32x4*)(void*)(C + (size_t)m * 1024 + nb) = c;
    }
  }
}

// ---------------- fused attention: R8 writeback + R5 q-tile chaining ----------------
// grid 512 = 64 bh x 8 chains of 4 q-tiles (256 rows). Sweep schedule:
// passA(t0) | passB(t0)+passA(t1) | ... | passB(t3)  -> 5 K-sweeps per 4 tiles (vs 8),
// pass A compute hides inside pass B's nt-store drain windows.
// Pass B per tile = R8: P (bf16) accumulates in wave-private LDS slab over 4-step
// batches; writeback = 512B-contiguous nt rows, NO barrier after stores.
// All tile-boundary syncs are BAR_LGKM (LDS-only: sml/Osum) so nt stores never drain.
#define LOADQF(dst, qrow0)                                                        \
  _Pragma("unroll")                                                               \
  for (int qc = 0; qc < 4; ++qc)                                                  \
    _Pragma("unroll")                                                             \
    for (int hf = 0; hf < 2; ++hf)                                                \
      dst[qc][hf] = *(const bf16x8*)(const void*)(Qb + (size_t)((qrow0) + qc * 16 + r) * 64 + hf * 32 + g * 8);

#define LOADKF(kf, kk)                                                            \
  _Pragma("unroll")                                                               \
  for (int ks = 0; ks < 2; ++ks)                                                  \
    _Pragma("unroll")                                                             \
    for (int hf = 0; hf < 2; ++hf)                                                \
      kf[ks][hf] = *(const bf16x8*)(const void*)(Kb + (size_t)((kk) + ks * 16 + r) * 64 + hf * 32 + g * 8);

#define LOADMP(mp0, mp1, kk)                                                      \
  {                                                                               \
    f32x4 mv0 = *(const f32x4*)(const void*)(mb + (kk) + g * 4);                  \
    f32x4 mv1 = *(const f32x4*)(const void*)(mb + (kk) + 16 + g * 4);             \
    _Pragma("unroll")                                                             \
    for (int j = 0; j < 4; ++j) { mp0[j] = mv0[j] * NEGM; mp1[j] = mv1[j] * NEGM; } \
  }

#define PASSA_CORE(qf, lreg, kf, mp0, mp1)                                        \
  _Pragma("unroll")                                                               \
  for (int qc = 0; qc < 4; ++qc) {                                                \
    f32x4 s0 = fz, s1 = fz;                                                       \
    s0 = mfma16(kf[0][0], qf[qc][0], s0);                                         \
    s0 = mfma16(kf[0][1], qf[qc][1], s0);                                         \
    s1 = mfma16(kf[1][0], qf[qc][0], s1);                                         \
    s1 = mfma16(kf[1][1], qf[qc][1], s1);                                         \
    float p = 0.f;                                                                \
    _Pragma("unroll")                                                             \
    for (int j = 0; j < 4; ++j) p += e2(s0[j] + mp0[j]) + e2(s1[j] + mp1[j]);     \
    lreg[qc] += p;                                                                \
  }

#define REDUCE_L(lreg)                                                            \
  _Pragma("unroll")                                                               \
  for (int qc = 0; qc < 4; ++qc) {                                                \
    lreg[qc] += __shfl_xor(lreg[qc], 16);                                         \
    lreg[qc] += __shfl_xor(lreg[qc], 32);                                         \
  }                                                                               \
  if (lane < 16) {                                                                \
    _Pragma("unroll")                                                             \
    for (int qc = 0; qc < 4; ++qc) sml[w][qc * 16 + lane] = lreg[qc];             \
  }

__global__ __launch_bounds__(256, 2) void attn_fused(const unsigned short* __restrict__ Qh,
                                                     const unsigned short* __restrict__ Kh,
                                                     const unsigned short* __restrict__ Vt,
                                                     const float* __restrict__ mask,
                                                     float* __restrict__ attn_out,
                                                     unsigned short* __restrict__ Obuf) {
  constexpr int PITCH = 138;  // u16 units; 69 dwords/row, 69 % 32 = 5 (odd, bank-friendly)
  __shared__ __align__(16) unsigned short PldsAll[4][64 * PITCH];  // 70656 B
  __shared__ float sml[4][64];

  const int blk = (blockIdx.x & 7) * 64 + (blockIdx.x >> 3);  // XCD swizzle (512%8==0)
  const int bh = blk >> 3;
  const int q0base = (blk & 7) << 8;  // chain of 4 q-tiles = 256 rows
  const int b = bh >> 4, h = bh & 15;
  const int tid = threadIdx.x;
  const int w = tid >> 6, lane = tid & 63, g = lane >> 4, r = lane & 15;
  const float NEGM = -1e9f * LOG2E;

  const unsigned short* Qb = Qh + (size_t)bh * (2048 * 64);
  const unsigned short* Kb = Kh + (size_t)bh * (2048 * 64);
  const unsigned short* Vb = Vt + (size_t)bh * (64 * 2048);
  const float* mb = mask + (size_t)b * 2048;
  const f32x4 fz = {0.f, 0.f, 0.f, 0.f};
  float* ab = attn_out + (size_t)bh * 2048 * 2048;
  unsigned short* Pw = &PldsAll[w][0];
  const int half = lane >> 5;   // writeback: 2 rows per instruction
  const int l5 = lane & 31;

  bf16x8 qfE[4][2], qfO[4][2];
  LOADQF(qfE, q0base)

  // ---- sweep 0: pure pass A for tile 0 ----
  {
    float lreg0[4] = {0.f, 0.f, 0.f, 0.f};
    for (int step = 0; step < 16; ++step) {
      const int kk = (w << 9) + (step << 5);
      bf16x8 kf[2][2];
      LOADKF(kf, kk)
      f32x4 mp0, mp1;
      LOADMP(mp0, mp1, kk)
      PASSA_CORE(qfE, lreg0, kf, mp0, mp1)
    }
    REDUCE_L(lreg0)
  }
  BAR_LGKM();

#pragma unroll
  for (int t = 0; t < 4; ++t) {
    bf16x8(&qa)[4][2] = (t & 1) ? qfO : qfE;
    bf16x8(&qb)[4][2] = (t & 1) ? qfE : qfO;
    const int q0 = q0base + t * 64;

    float cL[4];
#pragma unroll
    for (int qc = 0; qc < 4; ++qc) {
      const int q = qc * 16 + r;
      cL[qc] = -__log2f(sml[0][q] + sml[1][q] + sml[2][q] + sml[3][q]);
    }

    f32x4 oacc[4][4];
#pragma unroll
    for (int i = 0; i < 4; ++i)
#pragma unroll
      for (int j = 0; j < 4; ++j) oacc[i][j] = fz;

    float lregB[4] = {0.f, 0.f, 0.f, 0.f};
    if (t < 3) { LOADQF(qb, q0 + 64) }

    // ---- fused sweep: pass B (tile t, R8 batch structure) + pass A (tile t+1) ----
    for (int batch = 0; batch < 4; ++batch) {
#pragma unroll
      for (int sub = 0; sub < 4; ++sub) {
        const int step = batch * 4 + sub;
        const int kk = (w << 9) + (step << 5);
        bf16x8 kf[2][2];
        LOADKF(kf, kk)
        f32x4 mp0, mp1;
        LOADMP(mp0, mp1, kk)

#pragma unroll
        for (int ks = 0; ks < 2; ++ks) {
#pragma unroll
          for (int qc = 0; qc < 4; ++qc) {
            f32x4 s = fz;
            s = mfma16(kf[ks][0], qa[qc][0], s);
            s = mfma16(kf[ks][1], qa[qc][1], s);
            u16x4 pb;
#pragma unroll
            for (int j = 0; j < 4; ++j)
              pb[j] = bfc(e2(s[j] + (ks ? mp1[j] : mp0[j]) + cL[qc]));
            *(u16x4*)(void*)(&Pw[(qc * 16 + r) * PITCH + sub * 32 + ks * 16 + g * 4]) = pb;
          }
        }
        bf16x8 vf[4];
#pragma unroll
        for (int dn = 0; dn < 4; ++dn)
          vf[dn] = *(const bf16x8*)(const void*)(Vb + (size_t)(dn * 16 + r) * 2048 + kk + g * 8);
#pragma unroll
        for (int qs = 0; qs < 4; ++qs) {
          const bf16x8 pa = *(const bf16x8*)(const void*)(&Pw[(qs * 16 + r) * PITCH + sub * 32 + g * 8]);
#pragma unroll
          for (int dn = 0; dn < 4; ++dn) oacc[qs][dn] = mfma16(pa, vf[dn], oacc[qs][dn]);
        }
        if (t < 3) { PASSA_CORE(qb, lregB, kf, mp0, mp1) }
      }
      // ---- writeback: 64 rows x 128 cols (bf16->f32), 512B contiguous, nt, no sync ----
      const int colb = (w << 9) + (batch << 7);
#pragma unroll 4
      for (int i = 0; i < 32; ++i) {
        const int row = i * 2 + half;
        const u32x2 u = *(const u32x2*)(const void*)(&Pw[row * PITCH + l5 * 4]);
        f32x4 o;
        o[0] = fb(u[0] << 16);
        o[1] = fb(u[0] & 0xFFFF0000u);
        o[2] = fb(u[1] << 16);
        o[3] = fb(u[1] & 0xFFFF0000u);
        __builtin_nontemporal_store(
            o, (f32x4*)(void*)(ab + (size_t)(q0 + row) * 2048 + colb + l5 * 4));
      }
    }
    if (t < 3) { REDUCE_L(lregB) }  // sml for tile t+1 (read after tile-end barrier)

    // ---- reduce O across waves (Osum unioned into wave 0's dead slab) ----
    float (*Osum)[68] = reinterpret_cast<float (*)[68]>(&PldsAll[0][0]);
    for (int wv = 0; wv < 4; ++wv) {
      if (w == wv) {
#pragma unroll
        for (int qs = 0; qs < 4; ++qs)
#pragma unroll
          for (int dn = 0; dn < 4; ++dn)
#pragma unroll
            for (int j = 0; j < 4; ++j) {
              const int q = qs * 16 + g * 4 + j, d = dn * 16 + r;
              if (wv == 0) Osum[q][d] = oacc[qs][dn][j];
              else         Osum[q][d] += oacc[qs][dn][j];
            }
      }
      BAR_LGKM();
    }
    const int orow = tid >> 2, oc0 = (tid & 3) << 4;
#pragma unroll
    for (int hf2 = 0; hf2 < 2; ++hf2) {
      u16x8 pk;
#pragma unroll
      for (int j = 0; j < 8; ++j) pk[j] = bfc(Osum[orow][oc0 + hf2 * 8 + j]);
      *(u16x8*)(void*)(Obuf + (size_t)(b * 2048 + q0 + orow) * 1024 + h * 64 + oc0 + hf2 * 8) = pk;
    }
    BAR_LGKM();  // Osum reads + sml writes visible before next tile reuses slabs/sml
  }
}

// ---------------- launch ----------------
extern "C" void kernel_launch(void* const* d_in, const int* in_sizes, int n_in,
                              void* d_out, int out_size, void* d_ws, size_t ws_size,
                              hipStream_t stream) {
  const float* query = (const float*)d_in[0];
  const float* key_  = (const float*)d_in[1];
  const float* value = (const float*)d_in[2];
  const float* mask  = (const float*)d_in[3];
  const float* Wq = (const float*)d_in[4];
  const float* bq = (const float*)d_in[5];
  const float* Wk = (const float*)d_in[6];
  const float* bk = (const float*)d_in[7];
  const float* Wv = (const float*)d_in[8];
  const float* bv = (const float*)d_in[9];
  const float* Wo = (const float*)d_in[10];
  const float* bo = (const float*)d_in[11];

  uint8_t* ws = (uint8_t*)d_ws;
  unsigned short* XQ  = (unsigned short*)(ws);             // 16 MB bf16
  unsigned short* XK  = (unsigned short*)(ws + 16777216);
  unsigned short* XV  = (unsigned short*)(ws + 33554432);
  unsigned short* WTQ = (unsigned short*)(ws + 50331648);  // 2 MB each, [n][k]
  unsigned short* WTK = (unsigned short*)(ws + 52428800);
  unsigned short* WTV = (unsigned short*)(ws + 54525952);
  unsigned short* WTO = (unsigned short*)(ws + 56623104);
  unsigned short* QH  = (unsigned short*)(ws + 58720256);  // [bh][s][d] (pre-scaled)
  unsigned short* KH  = (unsigned short*)(ws + 75497472);  // [bh][s][d]
  unsigned short* VT  = (unsigned short*)(ws + 92274688);  // [bh][d][s]
  unsigned short* OB  = XQ;  // alias: XQ dead after gemm_qk

  float* outp = (float*)d_out;
  float* attnp = outp + 8388608;

  Ptr3 pc = {{query, key_, value}, {XQ, XK, XV}};
  cvt3<<<dim3(8192, 1, 3), 256, 0, stream>>>(pc);
  Ptr4 pw = {{Wq, Wk, Wv, Wo}, {WTQ, WTK, WTV, WTO}};
  wtrans4<<<dim3(32, 32, 4), 256, 0, stream>>>(pw);
  QKArgs qk = {{XQ, XK}, {WTQ, WTK}, {bq, bk}, {QH, KH}};
  gemm_qk<<<dim3(64, 8, 2), 256, 0, stream>>>(qk);
  gemm_v<<<dim3(64, 8), 256, 0, stream>>>(XV, WTV, bv, VT);
  attn_fused<<<512, 256, 0, stream>>>(QH, KH, VT, mask, attnp, OB);
  gemm_o<<<dim3(64, 8), 256, 0, stream>>>(OB, WTO, bo, outp);
}

// Round 15
// 448.956 us; speedup vs baseline: 1.3267x; 1.3267x over previous
//
#include <hip/hip_runtime.h>
#include <stdint.h>

// B=4, S=2048, D=1024, H=16, DEPTH=64
// out0: [B,S,D] f32 (8388608), out1: attn [B,H,S,S] f32 (268435456)

typedef float f32x4 __attribute__((ext_vector_type(4)));
typedef __bf16 bf16x8 __attribute__((ext_vector_type(8)));
typedef unsigned short u16x4 __attribute__((ext_vector_type(4)));
typedef unsigned short u16x8 __attribute__((ext_vector_type(8)));
typedef unsigned int u32x2 __attribute__((ext_vector_type(2)));

#define LOG2E 1.44269504088896340736f

static __device__ __forceinline__ f32x4 mfma16(bf16x8 a, bf16x8 b, f32x4 c) {
  return __builtin_amdgcn_mfma_f32_16x16x32_bf16(a, b, c, 0, 0, 0);
}
static __device__ __forceinline__ unsigned short bfc(float f) {
  return __builtin_bit_cast(unsigned short, (__bf16)f);
}
static __device__ __forceinline__ float e2(float x) { return __builtin_amdgcn_exp2f(x); }
static __device__ __forceinline__ float fb(unsigned int u) {
  return __builtin_bit_cast(float, u);
}

#define GLDS16(g, l)                                                    \
  __builtin_amdgcn_global_load_lds(                                     \
      (const __attribute__((address_space(1))) void*)(g),               \
      (__attribute__((address_space(3))) void*)(l), 16, 0, 0)

struct Ptr3 { const float* s[3]; unsigned short* d[3]; };
struct Ptr4 { const float* s[4]; unsigned short* d[4]; };
struct QKArgs {
  const unsigned short* A[2];
  const unsigned short* Bt[2];
  const float* bias[2];
  unsigned short* C[2];
};

// ---------------- f32 -> bf16 conversion (all 3 inputs, z-indexed) ----------------
__global__ void cvt3(Ptr3 p) {
  const int z = blockIdx.z;
  const int i = (blockIdx.x * 256 + threadIdx.x) * 4;
  f32x4 v = *(const f32x4*)(const void*)(p.s[z] + i);
  u16x4 o;
  o[0] = bfc(v[0]); o[1] = bfc(v[1]); o[2] = bfc(v[2]); o[3] = bfc(v[3]);
  *(u16x4*)(void*)(p.d[z] + i) = o;
}

// ---------------- W [k][n] f32 -> Wt [n][k] bf16 (all 4, z-indexed) ----------------
__global__ void wtrans4(Ptr4 p) {
  __shared__ float t[32][33];
  const int z = blockIdx.z;
  const float* W = p.s[z];
  unsigned short* Wt = p.d[z];
  const int tx = threadIdx.x & 31, ty = threadIdx.x >> 5;
  const int n0 = blockIdx.x * 32, k0 = blockIdx.y * 32;
#pragma unroll
  for (int i = 0; i < 4; ++i)
    t[ty + i * 8][tx] = W[(size_t)(k0 + ty + i * 8) * 1024 + n0 + tx];
  __syncthreads();
#pragma unroll
  for (int i = 0; i < 4; ++i)
    Wt[(size_t)(n0 + ty + i * 8) * 1024 + k0 + tx] = bfc(t[tx][ty + i * 8]);
}

// ===== shared GEMM core (m97 structure: BK=32, single LDS buffer) =====
#define GEMM_PROLOG(Aptr, Btptr)                                        \
  __shared__ unsigned short sA[128 * 32];                               \
  __shared__ unsigned short sB[128 * 32];                               \
  const int tid = threadIdx.x;                                          \
  const int m0 = blockIdx.x << 7, n0 = blockIdx.y << 7;                 \
  const int w = tid >> 6, lane = tid & 63, g = lane >> 4, r = lane & 15;\
  const int wr = w >> 1, wc = w & 1;                                    \
  const int srow = tid >> 2;                                            \
  const int scol = (tid & 3) << 3;                                      \
  const unsigned short* ga = (Aptr) + (size_t)(m0 + srow) * 1024 + scol;\
  const unsigned short* gb = (Btptr) + (size_t)(n0 + srow) * 1024 + scol;\
  unsigned short* la = sA + tid * 8;                                    \
  unsigned short* lb = sB + tid * 8;

#define GEMM_KLOOP(SWAP)                                                \
  for (int kt = 0; kt < 32; ++kt) {                                     \
    const int ko = kt << 5;                                             \
    GLDS16(ga + ko, la);                                                \
    GLDS16(ga + ko + 64 * 1024, la + 64 * 32);                          \
    GLDS16(gb + ko, lb);                                                \
    GLDS16(gb + ko + 64 * 1024, lb + 64 * 32);                          \
    __syncthreads();                                                    \
    bf16x8 af[4], bfv[4];                                               \
    _Pragma("unroll")                                                   \
    for (int i = 0; i < 4; ++i) {                                       \
      af[i]  = *(const bf16x8*)(const void*)&sA[(wr * 64 + i * 16 + r) * 32 + g * 8]; \
      bfv[i] = *(const bf16x8*)(const void*)&sB[(wc * 64 + i * 16 + r) * 32 + g * 8]; \
    }                                                                   \
    _Pragma("unroll")                                                   \
    for (int i = 0; i < 4; ++i)                                         \
      _Pragma("unroll")                                                 \
      for (int j = 0; j < 4; ++j)                                       \
        acc[i][j] = (SWAP) ? mfma16(bfv[j], af[i], acc[i][j])           \
                           : mfma16(af[i], bfv[j], acc[i][j]);          \
    __syncthreads();                                                    \
  }

// ---------------- Q/K GEMM (z=0: Q pre-scaled by 0.125*log2e, z=1: K) ----------------
__global__ __launch_bounds__(256, 2) void gemm_qk(QKArgs args) {
  const int z = blockIdx.z;
  const f32x4 fz = {0.f, 0.f, 0.f, 0.f};
  f32x4 acc[4][4];
#pragma unroll
  for (int i = 0; i < 4; ++i)
#pragma unroll
    for (int j = 0; j < 4; ++j) acc[i][j] = fz;
  GEMM_PROLOG(args.A[z], args.Bt[z])
  GEMM_KLOOP(1)  // acc[i][j]: regs->n (j*16+g*4+t), lane r->m (i*16+r)
  const float osc = (z == 0) ? (0.125f * LOG2E) : 1.0f;
  unsigned short* Cq = args.C[z];
  const float* bias = args.bias[z];
#pragma unroll
  for (int j = 0; j < 4; ++j) {
    const int nb = n0 + wc * 64 + j * 16 + g * 4;
    const f32x4 b4 = *(const f32x4*)(const void*)(bias + nb);
#pragma unroll
    for (int i = 0; i < 4; ++i) {
      const int m = m0 + wr * 64 + i * 16 + r;
      const int bb = m >> 11, s = m & 2047, hh = nb >> 6, d = nb & 63;
      u16x4 pk;
#pragma unroll
      for (int t = 0; t < 4; ++t) pk[t] = bfc((acc[i][j][t] + b4[t]) * osc);
      *(u16x4*)(void*)(Cq + (size_t)(bb * 16 + hh) * 131072 + (size_t)s * 64 + d) = pk;
    }
  }
}

// ---------------- V GEMM -> transposed per-head [bh][d][s] ----------------
__global__ __launch_bounds__(256, 2) void gemm_v(const unsigned short* __restrict__ A,
                                                 const unsigned short* __restrict__ Bt,
                                                 const float* __restrict__ bias,
                                                 unsigned short* __restrict__ C) {
  const f32x4 fz = {0.f, 0.f, 0.f, 0.f};
  f32x4 acc[4][4];
#pragma unroll
  for (int i = 0; i < 4; ++i)
#pragma unroll
    for (int j = 0; j < 4; ++j) acc[i][j] = fz;
  GEMM_PROLOG(A, Bt)
  GEMM_KLOOP(0)  // acc[i][j]: regs->m (i*16+g*4+t), lane r->n (j*16+r)
#pragma unroll
  for (int j = 0; j < 4; ++j) {
    const int n = n0 + wc * 64 + j * 16 + r;
    const float bv = bias[n];
    const int hh = n >> 6, d = n & 63;
#pragma unroll
    for (int i = 0; i < 4; ++i) {
      const int m = m0 + wr * 64 + i * 16 + g * 4;
      const int bb = m >> 11, s = m & 2047;
      u16x4 pk;
#pragma unroll
      for (int t = 0; t < 4; ++t) pk[t] = bfc(acc[i][j][t] + bv);
      *(u16x4*)(void*)(C + (size_t)(bb * 16 + hh) * 131072 + (size_t)d * 2048 + s) = pk;
    }
  }
}

// ---------------- output GEMM: f32 [m][n], swapped, 16B stores ----------------
__global__ __launch_bounds__(256, 2) void gemm_o(const unsigned short* __restrict__ A,
                                                 const unsigned short* __restrict__ Bt,
                                                 const float* __restrict__ bias,
                                                 float* __restrict__ C) {
  const f32x4 fz = {0.f, 0.f, 0.f, 0.f};
  f32x4 acc[4][4];
#pragma unroll
  for (int i = 0; i < 4; ++i)
#pragma unroll
    for (int j = 0; j < 4; ++j) acc[i][j] = fz;
  GEMM_PROLOG(A, Bt)
  GEMM_KLOOP(1)
#pragma unroll
  for (int j = 0; j < 4; ++j) {
    const int nb = n0 + wc * 64 + j * 16 + g * 4;
    const f32x4 b4 = *(const f32x4*)(const void*)(bias + nb);
#pragma unroll
    for (int i = 0; i < 4; ++i) {
      const int m = m0 + wr * 64 + i * 16 + r;
      f32x4 c;
#pragma unroll
      for (int t = 0; t < 4; ++t) c[t] = acc[i][j][t] + b4[t];
      *(f32x4*)(void*)(C + (size_t)m * 1024 + nb) = c;
    }
  }
}

// ---------------- fused attention: LDS-batched P writeback (R8, best known) ----------------
// QBLK=64, grid 2048, XCD swizzle, Q pre-scaled, cL fold, no-max, branchless mask.
// Pass B accumulates P (bf16) in a per-wave LDS band [64][128] over 4 steps
// (pitch 138 = 69 dwords, 69%32=5 -> PV b128 reads <=2-way conflicts);
// every 4 steps the wave reads rows back, expands bf16->f32 (<<16), and nt-stores
// 512B-contiguous per row, rows sequential -> DRAM page efficiency 4x vs 64B scatter.
// NO barrier anywhere near the store bursts (R9/R11/R12/R13 all regressed adding
// cooperative/barrier'd variants). Osum unioned into wave-0's dead P slab.
__global__ __launch_bounds__(256, 2) void attn_fused(const unsigned short* __restrict__ Qh,
                                                     const unsigned short* __restrict__ Kh,
                                                     const unsigned short* __restrict__ Vt,
                                                     const float* __restrict__ mask,
                                                     float* __restrict__ attn_out,
                                                     unsigned short* __restrict__ Obuf) {
  constexpr int PITCH = 138;  // u16 units; 69 dwords/row, 69 % 32 = 5 (odd, bank-friendly)
  __shared__ __align__(16) unsigned short PldsAll[4][64 * PITCH];  // 70656 B
  __shared__ float sml[4][64];

  const int blk = (blockIdx.x & 7) * 256 + (blockIdx.x >> 3);  // XCD swizzle (2048%8==0)
  const int bh = blk >> 5;
  const int q0 = (blk & 31) << 6;
  const int b = bh >> 4, h = bh & 15;
  const int tid = threadIdx.x;
  const int w = tid >> 6, lane = tid & 63, g = lane >> 4, r = lane & 15;
  const float NEGM = -1e9f * LOG2E;

  const unsigned short* Qb = Qh + (size_t)bh * (2048 * 64);
  const unsigned short* Kb = Kh + (size_t)bh * (2048 * 64);
  const unsigned short* Vb = Vt + (size_t)bh * (64 * 2048);
  const float* mb = mask + (size_t)b * 2048;
  const f32x4 fz = {0.f, 0.f, 0.f, 0.f};

  bf16x8 qf[4][2];
#pragma unroll
  for (int qc = 0; qc < 4; ++qc)
#pragma unroll
    for (int hf = 0; hf < 2; ++hf)
      qf[qc][hf] = *(const bf16x8*)(const void*)(Qb + (size_t)(q0 + qc * 16 + r) * 64 + hf * 32 + g * 8);

  float lreg[4] = {0.f, 0.f, 0.f, 0.f};

  // ---- pass A: row sums of exp2(logits) over this wave's 512 keys ----
  for (int step = 0; step < 16; ++step) {
    const int kk = (w << 9) + (step << 5);
    bf16x8 kf[2][2];
#pragma unroll
    for (int ks = 0; ks < 2; ++ks)
#pragma unroll
      for (int hf = 0; hf < 2; ++hf)
        kf[ks][hf] = *(const bf16x8*)(const void*)(Kb + (size_t)(kk + ks * 16 + r) * 64 + hf * 32 + g * 8);
    f32x4 mv0 = *(const f32x4*)(const void*)(mb + kk + g * 4);
    f32x4 mv1 = *(const f32x4*)(const void*)(mb + kk + 16 + g * 4);
    f32x4 mp0, mp1;
#pragma unroll
    for (int j = 0; j < 4; ++j) { mp0[j] = mv0[j] * NEGM; mp1[j] = mv1[j] * NEGM; }

#pragma unroll
    for (int qc = 0; qc < 4; ++qc) {
      f32x4 s0 = fz, s1 = fz;
      s0 = mfma16(kf[0][0], qf[qc][0], s0);
      s0 = mfma16(kf[0][1], qf[qc][1], s0);
      s1 = mfma16(kf[1][0], qf[qc][0], s1);
      s1 = mfma16(kf[1][1], qf[qc][1], s1);
      float p = 0.f;
#pragma unroll
      for (int j = 0; j < 4; ++j) p += e2(s0[j] + mp0[j]) + e2(s1[j] + mp1[j]);
      lreg[qc] += p;
    }
  }
#pragma unroll
  for (int qc = 0; qc < 4; ++qc) {
    lreg[qc] += __shfl_xor(lreg[qc], 16);
    lreg[qc] += __shfl_xor(lreg[qc], 32);
  }
  if (lane < 16) {
#pragma unroll
    for (int qc = 0; qc < 4; ++qc) sml[w][qc * 16 + lane] = lreg[qc];
  }
  __syncthreads();
  float cL[4];
#pragma unroll
  for (int qc = 0; qc < 4; ++qc) {
    const int q = qc * 16 + r;
    cL[qc] = -__log2f(sml[0][q] + sml[1][q] + sml[2][q] + sml[3][q]);
  }

  f32x4 oacc[4][4];
#pragma unroll
  for (int i = 0; i < 4; ++i)
#pragma unroll
    for (int j = 0; j < 4; ++j) oacc[i][j] = fz;

  float* ab = attn_out + (size_t)bh * 2048 * 2048;
  unsigned short* Pw = &PldsAll[w][0];
  const int half = lane >> 5;   // writeback: 2 rows per instruction
  const int l5 = lane & 31;

  // ---- pass B: 4 batches x 4 steps; P -> LDS band; batched contiguous writeback ----
  for (int batch = 0; batch < 4; ++batch) {
#pragma unroll
    for (int sub = 0; sub < 4; ++sub) {
      const int step = batch * 4 + sub;
      const int kk = (w << 9) + (step << 5);
      bf16x8 kf[2][2];
#pragma unroll
      for (int ks = 0; ks < 2; ++ks)
#pragma unroll
        for (int hf = 0; hf < 2; ++hf)
          kf[ks][hf] = *(const bf16x8*)(const void*)(Kb + (size_t)(kk + ks * 16 + r) * 64 + hf * 32 + g * 8);
      f32x4 mv0 = *(const f32x4*)(const void*)(mb + kk + g * 4);
      f32x4 mv1 = *(const f32x4*)(const void*)(mb + kk + 16 + g * 4);
      f32x4 mp[2];
#pragma unroll
      for (int j = 0; j < 4; ++j) { mp[0][j] = mv0[j] * NEGM; mp[1][j] = mv1[j] * NEGM; }

#pragma unroll
      for (int ks = 0; ks < 2; ++ks) {
#pragma unroll
        for (int qc = 0; qc < 4; ++qc) {
          f32x4 s = fz;
          s = mfma16(kf[ks][0], qf[qc][0], s);
          s = mfma16(kf[ks][1], qf[qc][1], s);
          u16x4 pb;
#pragma unroll
          for (int j = 0; j < 4; ++j) pb[j] = bfc(e2(s[j] + mp[ks][j] + cL[qc]));
          *(u16x4*)(void*)(&Pw[(qc * 16 + r) * PITCH + sub * 32 + ks * 16 + g * 4]) = pb;
        }
      }
      bf16x8 vf[4];
#pragma unroll
      for (int dn = 0; dn < 4; ++dn)
        vf[dn] = *(const bf16x8*)(const void*)(Vb + (size_t)(dn * 16 + r) * 2048 + kk + g * 8);
#pragma unroll
      for (int qs = 0; qs < 4; ++qs) {
        const bf16x8 pa = *(const bf16x8*)(const void*)(&Pw[(qs * 16 + r) * PITCH + sub * 32 + g * 8]);
#pragma unroll
        for (int dn = 0; dn < 4; ++dn) oacc[qs][dn] = mfma16(pa, vf[dn], oacc[qs][dn]);
      }
    }
    // ---- writeback: 64 rows x 128 cols (bf16->f32), 512B contiguous per row ----
    const int colb = (w << 9) + (batch << 7);
#pragma unroll 4
    for (int i = 0; i < 32; ++i) {
      const int row = i * 2 + half;
      const u32x2 u = *(const u32x2*)(const void*)(&Pw[row * PITCH + l5 * 4]);
      f32x4 o;
      o[0] = fb(u[0] << 16);
      o[1] = fb(u[0] & 0xFFFF0000u);
      o[2] = fb(u[1] << 16);
      o[3] = fb(u[1] & 0xFFFF0000u);
      __builtin_nontemporal_store(
          o, (f32x4*)(void*)(ab + (size_t)(q0 + row) * 2048 + colb + l5 * 4));
    }
  }

  // ---- reduce O across waves (disjoint 512-key partials) ----
  // Osum unioned into wave 0's P slab (17408 B <= 17664 B); wave 0 is done with it.
  float (*Osum)[68] = reinterpret_cast<float (*)[68]>(&PldsAll[0][0]);
  for (int wv = 0; wv < 4; ++wv) {
    if (w == wv) {
#pragma unroll
      for (int qs = 0; qs < 4; ++qs)
#pragma unroll
        for (int dn = 0; dn < 4; ++dn)
#pragma unroll
          for (int j = 0; j < 4; ++j) {
            const int q = qs * 16 + g * 4 + j, d = dn * 16 + r;
            if (wv == 0) Osum[q][d] = oacc[qs][dn][j];
            else         Osum[q][d] += oacc[qs][dn][j];
          }
    }
    __syncthreads();
  }
  const int orow = tid >> 2, oc0 = (tid & 3) << 4;
#pragma unroll
  for (int hf2 = 0; hf2 < 2; ++hf2) {
    u16x8 pk;
#pragma unroll
    for (int j = 0; j < 8; ++j) pk[j] = bfc(Osum[orow][oc0 + hf2 * 8 + j]);
    *(u16x8*)(void*)(Obuf + (size_t)(b * 2048 + q0 + orow) * 1024 + h * 64 + oc0 + hf2 * 8) = pk;
  }
}

// ---------------- launch ----------------
extern "C" void kernel_launch(void* const* d_in, const int* in_sizes, int n_in,
                              void* d_out, int out_size, void* d_ws, size_t ws_size,
                              hipStream_t stream) {
  const float* query = (const float*)d_in[0];
  const float* key_  = (const float*)d_in[1];
  const float* value = (const float*)d_in[2];
  const float* mask  = (const float*)d_in[3];
  const float* Wq = (const float*)d_in[4];
  const float* bq = (const float*)d_in[5];
  const float* Wk = (const float*)d_in[6];
  const float* bk = (const float*)d_in[7];
  const float* Wv = (const float*)d_in[8];
  const float* bv = (const float*)d_in[9];
  const float* Wo = (const float*)d_in[10];
  const float* bo = (const float*)d_in[11];

  uint8_t* ws = (uint8_t*)d_ws;
  unsigned short* XQ  = (unsigned short*)(ws);             // 16 MB bf16
  unsigned short* XK  = (unsigned short*)(ws + 16777216);
  unsigned short* XV  = (unsigned short*)(ws + 33554432);
  unsigned short* WTQ = (unsigned short*)(ws + 50331648);  // 2 MB each, [n][k]
  unsigned short* WTK = (unsigned short*)(ws + 52428800);
  unsigned short* WTV = (unsigned short*)(ws + 54525952);
  unsigned short* WTO = (unsigned short*)(ws + 56623104);
  unsigned short* QH  = (unsigned short*)(ws + 58720256);  // [bh][s][d] (pre-scaled)
  unsigned short* KH  = (unsigned short*)(ws + 75497472);  // [bh][s][d]
  unsigned short* VT  = (unsigned short*)(ws + 92274688);  // [bh][d][s]
  unsigned short* OB  = XQ;  // alias: XQ dead after gemm_qk

  float* outp = (float*)d_out;
  float* attnp = outp + 8388608;

  Ptr3 pc = {{query, key_, value}, {XQ, XK, XV}};
  cvt3<<<dim3(8192, 1, 3), 256, 0, stream>>>(pc);
  Ptr4 pw = {{Wq, Wk, Wv, Wo}, {WTQ, WTK, WTV, WTO}};
  wtrans4<<<dim3(32, 32, 4), 256, 0, stream>>>(pw);
  QKArgs qk = {{XQ, XK}, {WTQ, WTK}, {bq, bk}, {QH, KH}};
  gemm_qk<<<dim3(64, 8, 2), 256, 0, stream>>>(qk);
  gemm_v<<<dim3(64, 8), 256, 0, stream>>>(XV, WTV, bv, VT);
  attn_fused<<<2048, 256, 0, stream>>>(QH, KH, VT, mask, attnp, OB);
  gemm_o<<<dim3(64, 8), 256, 0, stream>>>(OB, WTO, bo, outp);
}

// Round 16
// 438.256 us; speedup vs baseline: 1.3591x; 1.0244x over previous
//
#include <hip/hip_runtime.h>
#include <stdint.h>

// B=4, S=2048, D=1024, H=16, DEPTH=64
// out0: [B,S,D] f32 (8388608), out1: attn [B,H,S,S] f32 (268435456)

typedef float f32x4 __attribute__((ext_vector_type(4)));
typedef __bf16 bf16x8 __attribute__((ext_vector_type(8)));
typedef unsigned short u16x4 __attribute__((ext_vector_type(4)));
typedef unsigned short u16x8 __attribute__((ext_vector_type(8)));
typedef unsigned int u32x2 __attribute__((ext_vector_type(2)));

#define LOG2E 1.44269504088896340736f

static __device__ __forceinline__ f32x4 mfma16(bf16x8 a, bf16x8 b, f32x4 c) {
  return __builtin_amdgcn_mfma_f32_16x16x32_bf16(a, b, c, 0, 0, 0);
}
static __device__ __forceinline__ unsigned short bfc(float f) {
  return __builtin_bit_cast(unsigned short, (__bf16)f);
}
static __device__ __forceinline__ float e2(float x) { return __builtin_amdgcn_exp2f(x); }
static __device__ __forceinline__ float fb(unsigned int u) {
  return __builtin_bit_cast(float, u);
}

#define GLDS16(g, l)                                                    \
  __builtin_amdgcn_global_load_lds(                                     \
      (const __attribute__((address_space(1))) void*)(g),               \
      (__attribute__((address_space(3))) void*)(l), 16, 0, 0)

struct PrepArgs {
  const float* x[3]; unsigned short* y[3];
  const float* W[4]; unsigned short* Wt[4];
};
struct QKVArgs {
  const unsigned short* A[3];
  const unsigned short* Bt[3];
  const float* bias[3];
  unsigned short* C[3];
};

// ---------------- prep: cvt (Q,K,V f32->bf16, 8/thread) + 4 weight transposes ----------------
// blocks [0,12288): cvt; z = bx>>12, 4096 blocks per tensor, 8 f32/thread.
// blocks [12288,16384): wtrans; z = (bx-12288)>>10, 1024 blocks per weight (32x32 tiles).
__global__ void prep(PrepArgs p) {
  __shared__ float t[32][33];
  const int bx = blockIdx.x;
  const int tid = threadIdx.x;
  if (bx < 12288) {
    const int z = bx >> 12, xb = bx & 4095;
    const size_t i = ((size_t)xb * 256 + tid) * 8;
    const f32x4 v0 = *(const f32x4*)(const void*)(p.x[z] + i);
    const f32x4 v1 = *(const f32x4*)(const void*)(p.x[z] + i + 4);
    u16x8 o;
    o[0] = bfc(v0[0]); o[1] = bfc(v0[1]); o[2] = bfc(v0[2]); o[3] = bfc(v0[3]);
    o[4] = bfc(v1[0]); o[5] = bfc(v1[1]); o[6] = bfc(v1[2]); o[7] = bfc(v1[3]);
    *(u16x8*)(void*)(p.y[z] + i) = o;
  } else {
    const int b2 = bx - 12288;
    const int z = b2 >> 10, rem = b2 & 1023;
    const float* W = p.W[z];
    unsigned short* Wt = p.Wt[z];
    const int tx = tid & 31, ty = tid >> 5;
    const int n0 = (rem & 31) * 32, k0 = (rem >> 5) * 32;
#pragma unroll
    for (int i = 0; i < 4; ++i)
      t[ty + i * 8][tx] = W[(size_t)(k0 + ty + i * 8) * 1024 + n0 + tx];
    __syncthreads();
#pragma unroll
    for (int i = 0; i < 4; ++i)
      Wt[(size_t)(n0 + ty + i * 8) * 1024 + k0 + tx] = bfc(t[tx][ty + i * 8]);
  }
}

// ===== shared GEMM core (m97 structure: BK=32, single LDS buffer) =====
#define GEMM_PROLOG(Aptr, Btptr)                                        \
  __shared__ unsigned short sA[128 * 32];                               \
  __shared__ unsigned short sB[128 * 32];                               \
  const int tid = threadIdx.x;                                          \
  const int m0 = blockIdx.x << 7, n0 = blockIdx.y << 7;                 \
  const int w = tid >> 6, lane = tid & 63, g = lane >> 4, r = lane & 15;\
  const int wr = w >> 1, wc = w & 1;                                    \
  const int srow = tid >> 2;                                            \
  const int scol = (tid & 3) << 3;                                      \
  const unsigned short* ga = (Aptr) + (size_t)(m0 + srow) * 1024 + scol;\
  const unsigned short* gb = (Btptr) + (size_t)(n0 + srow) * 1024 + scol;\
  unsigned short* la = sA + tid * 8;                                    \
  unsigned short* lb = sB + tid * 8;

#define GEMM_KLOOP(SWAP)                                                \
  for (int kt = 0; kt < 32; ++kt) {                                     \
    const int ko = kt << 5;                                             \
    GLDS16(ga + ko, la);                                                \
    GLDS16(ga + ko + 64 * 1024, la + 64 * 32);                          \
    GLDS16(gb + ko, lb);                                                \
    GLDS16(gb + ko + 64 * 1024, lb + 64 * 32);                          \
    __syncthreads();                                                    \
    bf16x8 af[4], bfv[4];                                               \
    _Pragma("unroll")                                                   \
    for (int i = 0; i < 4; ++i) {                                       \
      af[i]  = *(const bf16x8*)(const void*)&sA[(wr * 64 + i * 16 + r) * 32 + g * 8]; \
      bfv[i] = *(const bf16x8*)(const void*)&sB[(wc * 64 + i * 16 + r) * 32 + g * 8]; \
    }                                                                   \
    _Pragma("unroll")                                                   \
    for (int i = 0; i < 4; ++i)                                         \
      _Pragma("unroll")                                                 \
      for (int j = 0; j < 4; ++j)                                       \
        acc[i][j] = (SWAP) ? mfma16(bfv[j], af[i], acc[i][j])           \
                           : mfma16(af[i], bfv[j], acc[i][j]);          \
    __syncthreads();                                                    \
  }

// ---------------- Q/K/V GEMM in one dispatch (z=0:Q pre-scaled, 1:K, 2:V^T) ----------------
__global__ __launch_bounds__(256, 2) void gemm_qkv(QKVArgs args) {
  const int z = blockIdx.z;
  const f32x4 fz = {0.f, 0.f, 0.f, 0.f};
  f32x4 acc[4][4];
#pragma unroll
  for (int i = 0; i < 4; ++i)
#pragma unroll
    for (int j = 0; j < 4; ++j) acc[i][j] = fz;
  GEMM_PROLOG(args.A[z], args.Bt[z])
  const float* bias = args.bias[z];
  if (z < 2) {
    GEMM_KLOOP(1)  // acc[i][j]: regs->n (j*16+g*4+t), lane r->m (i*16+r)
    const float osc = (z == 0) ? (0.125f * LOG2E) : 1.0f;
    unsigned short* Cq = args.C[z];
#pragma unroll
    for (int j = 0; j < 4; ++j) {
      const int nb = n0 + wc * 64 + j * 16 + g * 4;
      const f32x4 b4 = *(const f32x4*)(const void*)(bias + nb);
#pragma unroll
      for (int i = 0; i < 4; ++i) {
        const int m = m0 + wr * 64 + i * 16 + r;
        const int bb = m >> 11, s = m & 2047, hh = nb >> 6, d = nb & 63;
        u16x4 pk;
#pragma unroll
        for (int t = 0; t < 4; ++t) pk[t] = bfc((acc[i][j][t] + b4[t]) * osc);
        *(u16x4*)(void*)(Cq + (size_t)(bb * 16 + hh) * 131072 + (size_t)s * 64 + d) = pk;
      }
    }
  } else {
    GEMM_KLOOP(0)  // acc[i][j]: regs->m (i*16+g*4+t), lane r->n (j*16+r)
    unsigned short* C = args.C[2];
#pragma unroll
    for (int j = 0; j < 4; ++j) {
      const int n = n0 + wc * 64 + j * 16 + r;
      const float bv = bias[n];
      const int hh = n >> 6, d = n & 63;
#pragma unroll
      for (int i = 0; i < 4; ++i) {
        const int m = m0 + wr * 64 + i * 16 + g * 4;
        const int bb = m >> 11, s = m & 2047;
        u16x4 pk;
#pragma unroll
        for (int t = 0; t < 4; ++t) pk[t] = bfc(acc[i][j][t] + bv);
        *(u16x4*)(void*)(C + (size_t)(bb * 16 + hh) * 131072 + (size_t)d * 2048 + s) = pk;
      }
    }
  }
}

// ---------------- output GEMM: f32 [m][n], swapped, 16B stores ----------------
__global__ __launch_bounds__(256, 2) void gemm_o(const unsigned short* __restrict__ A,
                                                 const unsigned short* __restrict__ Bt,
                                                 const float* __restrict__ bias,
                                                 float* __restrict__ C) {
  const f32x4 fz = {0.f, 0.f, 0.f, 0.f};
  f32x4 acc[4][4];
#pragma unroll
  for (int i = 0; i < 4; ++i)
#pragma unroll
    for (int j = 0; j < 4; ++j) acc[i][j] = fz;
  GEMM_PROLOG(A, Bt)
  GEMM_KLOOP(1)
#pragma unroll
  for (int j = 0; j < 4; ++j) {
    const int nb = n0 + wc * 64 + j * 16 + g * 4;
    const f32x4 b4 = *(const f32x4*)(const void*)(bias + nb);
#pragma unroll
    for (int i = 0; i < 4; ++i) {
      const int m = m0 + wr * 64 + i * 16 + r;
      f32x4 c;
#pragma unroll
      for (int t = 0; t < 4; ++t) c[t] = acc[i][j][t] + b4[t];
      *(f32x4*)(void*)(C + (size_t)m * 1024 + nb) = c;
    }
  }
}

// ---------------- fused attention: LDS-batched P writeback (R8, best known) ----------------
// QBLK=64, grid 2048, XCD swizzle, Q pre-scaled, cL fold, no-max, branchless mask.
// Pass B accumulates P (bf16) in a per-wave LDS band [64][128] over 4 steps
// (pitch 138 = 69 dwords, 69%32=5 -> PV b128 reads <=2-way conflicts);
// every 4 steps the wave reads rows back, expands bf16->f32 (<<16), and nt-stores
// 512B-contiguous per row, rows sequential. NO barrier near the store bursts
// (R9/R11/R12/R13 all regressed). Osum unioned into wave-0's dead P slab.
__global__ __launch_bounds__(256, 2) void attn_fused(const unsigned short* __restrict__ Qh,
                                                     const unsigned short* __restrict__ Kh,
                                                     const unsigned short* __restrict__ Vt,
                                                     const float* __restrict__ mask,
                                                     float* __restrict__ attn_out,
                                                     unsigned short* __restrict__ Obuf) {
  constexpr int PITCH = 138;  // u16 units; 69 dwords/row, 69 % 32 = 5 (odd, bank-friendly)
  __shared__ __align__(16) unsigned short PldsAll[4][64 * PITCH];  // 70656 B
  __shared__ float sml[4][64];

  const int blk = (blockIdx.x & 7) * 256 + (blockIdx.x >> 3);  // XCD swizzle (2048%8==0)
  const int bh = blk >> 5;
  const int q0 = (blk & 31) << 6;
  const int b = bh >> 4, h = bh & 15;
  const int tid = threadIdx.x;
  const int w = tid >> 6, lane = tid & 63, g = lane >> 4, r = lane & 15;
  const float NEGM = -1e9f * LOG2E;

  const unsigned short* Qb = Qh + (size_t)bh * (2048 * 64);
  const unsigned short* Kb = Kh + (size_t)bh * (2048 * 64);
  const unsigned short* Vb = Vt + (size_t)bh * (64 * 2048);
  const float* mb = mask + (size_t)b * 2048;
  const f32x4 fz = {0.f, 0.f, 0.f, 0.f};

  bf16x8 qf[4][2];
#pragma unroll
  for (int qc = 0; qc < 4; ++qc)
#pragma unroll
    for (int hf = 0; hf < 2; ++hf)
      qf[qc][hf] = *(const bf16x8*)(const void*)(Qb + (size_t)(q0 + qc * 16 + r) * 64 + hf * 32 + g * 8);

  float lreg[4] = {0.f, 0.f, 0.f, 0.f};

  // ---- pass A: row sums of exp2(logits) over this wave's 512 keys ----
  for (int step = 0; step < 16; ++step) {
    const int kk = (w << 9) + (step << 5);
    bf16x8 kf[2][2];
#pragma unroll
    for (int ks = 0; ks < 2; ++ks)
#pragma unroll
      for (int hf = 0; hf < 2; ++hf)
        kf[ks][hf] = *(const bf16x8*)(const void*)(Kb + (size_t)(kk + ks * 16 + r) * 64 + hf * 32 + g * 8);
    f32x4 mv0 = *(const f32x4*)(const void*)(mb + kk + g * 4);
    f32x4 mv1 = *(const f32x4*)(const void*)(mb + kk + 16 + g * 4);
    f32x4 mp0, mp1;
#pragma unroll
    for (int j = 0; j < 4; ++j) { mp0[j] = mv0[j] * NEGM; mp1[j] = mv1[j] * NEGM; }

#pragma unroll
    for (int qc = 0; qc < 4; ++qc) {
      f32x4 s0 = fz, s1 = fz;
      s0 = mfma16(kf[0][0], qf[qc][0], s0);
      s0 = mfma16(kf[0][1], qf[qc][1], s0);
      s1 = mfma16(kf[1][0], qf[qc][0], s1);
      s1 = mfma16(kf[1][1], qf[qc][1], s1);
      float p = 0.f;
#pragma unroll
      for (int j = 0; j < 4; ++j) p += e2(s0[j] + mp0[j]) + e2(s1[j] + mp1[j]);
      lreg[qc] += p;
    }
  }
#pragma unroll
  for (int qc = 0; qc < 4; ++qc) {
    lreg[qc] += __shfl_xor(lreg[qc], 16);
    lreg[qc] += __shfl_xor(lreg[qc], 32);
  }
  if (lane < 16) {
#pragma unroll
    for (int qc = 0; qc < 4; ++qc) sml[w][qc * 16 + lane] = lreg[qc];
  }
  __syncthreads();
  float cL[4];
#pragma unroll
  for (int qc = 0; qc < 4; ++qc) {
    const int q = qc * 16 + r;
    cL[qc] = -__log2f(sml[0][q] + sml[1][q] + sml[2][q] + sml[3][q]);
  }

  f32x4 oacc[4][4];
#pragma unroll
  for (int i = 0; i < 4; ++i)
#pragma unroll
    for (int j = 0; j < 4; ++j) oacc[i][j] = fz;

  float* ab = attn_out + (size_t)bh * 2048 * 2048;
  unsigned short* Pw = &PldsAll[w][0];
  const int half = lane >> 5;   // writeback: 2 rows per instruction
  const int l5 = lane & 31;

  // ---- pass B: 4 batches x 4 steps; P -> LDS band; batched contiguous writeback ----
  for (int batch = 0; batch < 4; ++batch) {
#pragma unroll
    for (int sub = 0; sub < 4; ++sub) {
      const int step = batch * 4 + sub;
      const int kk = (w << 9) + (step << 5);
      bf16x8 kf[2][2];
#pragma unroll
      for (int ks = 0; ks < 2; ++ks)
#pragma unroll
        for (int hf = 0; hf < 2; ++hf)
          kf[ks][hf] = *(const bf16x8*)(const void*)(Kb + (size_t)(kk + ks * 16 + r) * 64 + hf * 32 + g * 8);
      f32x4 mv0 = *(const f32x4*)(const void*)(mb + kk + g * 4);
      f32x4 mv1 = *(const f32x4*)(const void*)(mb + kk + 16 + g * 4);
      f32x4 mp[2];
#pragma unroll
      for (int j = 0; j < 4; ++j) { mp[0][j] = mv0[j] * NEGM; mp[1][j] = mv1[j] * NEGM; }

#pragma unroll
      for (int ks = 0; ks < 2; ++ks) {
#pragma unroll
        for (int qc = 0; qc < 4; ++qc) {
          f32x4 s = fz;
          s = mfma16(kf[ks][0], qf[qc][0], s);
          s = mfma16(kf[ks][1], qf[qc][1], s);
          u16x4 pb;
#pragma unroll
          for (int j = 0; j < 4; ++j) pb[j] = bfc(e2(s[j] + mp[ks][j] + cL[qc]));
          *(u16x4*)(void*)(&Pw[(qc * 16 + r) * PITCH + sub * 32 + ks * 16 + g * 4]) = pb;
        }
      }
      bf16x8 vf[4];
#pragma unroll
      for (int dn = 0; dn < 4; ++dn)
        vf[dn] = *(const bf16x8*)(const void*)(Vb + (size_t)(dn * 16 + r) * 2048 + kk + g * 8);
#pragma unroll
      for (int qs = 0; qs < 4; ++qs) {
        const bf16x8 pa = *(const bf16x8*)(const void*)(&Pw[(qs * 16 + r) * PITCH + sub * 32 + g * 8]);
#pragma unroll
        for (int dn = 0; dn < 4; ++dn) oacc[qs][dn] = mfma16(pa, vf[dn], oacc[qs][dn]);
      }
    }
    // ---- writeback: 64 rows x 128 cols (bf16->f32), 512B contiguous per row ----
    const int colb = (w << 9) + (batch << 7);
#pragma unroll 4
    for (int i = 0; i < 32; ++i) {
      const int row = i * 2 + half;
      const u32x2 u = *(const u32x2*)(const void*)(&Pw[row * PITCH + l5 * 4]);
      f32x4 o;
      o[0] = fb(u[0] << 16);
      o[1] = fb(u[0] & 0xFFFF0000u);
      o[2] = fb(u[1] << 16);
      o[3] = fb(u[1] & 0xFFFF0000u);
      __builtin_nontemporal_store(
          o, (f32x4*)(void*)(ab + (size_t)(q0 + row) * 2048 + colb + l5 * 4));
    }
  }

  // ---- reduce O across waves (disjoint 512-key partials) ----
  // Osum unioned into wave 0's P slab (17408 B <= 17664 B); wave 0 is done with it.
  float (*Osum)[68] = reinterpret_cast<float (*)[68]>(&PldsAll[0][0]);
  for (int wv = 0; wv < 4; ++wv) {
    if (w == wv) {
#pragma unroll
      for (int qs = 0; qs < 4; ++qs)
#pragma unroll
        for (int dn = 0; dn < 4; ++dn)
#pragma unroll
          for (int j = 0; j < 4; ++j) {
            const int q = qs * 16 + g * 4 + j, d = dn * 16 + r;
            if (wv == 0) Osum[q][d] = oacc[qs][dn][j];
            else         Osum[q][d] += oacc[qs][dn][j];
          }
    }
    __syncthreads();
  }
  const int orow = tid >> 2, oc0 = (tid & 3) << 4;
#pragma unroll
  for (int hf2 = 0; hf2 < 2; ++hf2) {
    u16x8 pk;
#pragma unroll
    for (int j = 0; j < 8; ++j) pk[j] = bfc(Osum[orow][oc0 + hf2 * 8 + j]);
    *(u16x8*)(void*)(Obuf + (size_t)(b * 2048 + q0 + orow) * 1024 + h * 64 + oc0 + hf2 * 8) = pk;
  }
}

// ---------------- launch ----------------
extern "C" void kernel_launch(void* const* d_in, const int* in_sizes, int n_in,
                              void* d_out, int out_size, void* d_ws, size_t ws_size,
                              hipStream_t stream) {
  const float* query = (const float*)d_in[0];
  const float* key_  = (const float*)d_in[1];
  const float* value = (const float*)d_in[2];
  const float* mask  = (const float*)d_in[3];
  const float* Wq = (const float*)d_in[4];
  const float* bq = (const float*)d_in[5];
  const float* Wk = (const float*)d_in[6];
  const float* bk = (const float*)d_in[7];
  const float* Wv = (const float*)d_in[8];
  const float* bv = (const float*)d_in[9];
  const float* Wo = (const float*)d_in[10];
  const float* bo = (const float*)d_in[11];

  uint8_t* ws = (uint8_t*)d_ws;
  unsigned short* XQ  = (unsigned short*)(ws);             // 16 MB bf16
  unsigned short* XK  = (unsigned short*)(ws + 16777216);
  unsigned short* XV  = (unsigned short*)(ws + 33554432);
  unsigned short* WTQ = (unsigned short*)(ws + 50331648);  // 2 MB each, [n][k]
  unsigned short* WTK = (unsigned short*)(ws + 52428800);
  unsigned short* WTV = (unsigned short*)(ws + 54525952);
  unsigned short* WTO = (unsigned short*)(ws + 56623104);
  unsigned short* QH  = (unsigned short*)(ws + 58720256);  // [bh][s][d] (pre-scaled)
  unsigned short* KH  = (unsigned short*)(ws + 75497472);  // [bh][s][d]
  unsigned short* VT  = (unsigned short*)(ws + 92274688);  // [bh][d][s]
  unsigned short* OB  = XQ;  // alias: XQ dead after gemm_qkv

  float* outp = (float*)d_out;
  float* attnp = outp + 8388608;

  PrepArgs pa = {{query, key_, value}, {XQ, XK, XV},
                 {Wq, Wk, Wv, Wo}, {WTQ, WTK, WTV, WTO}};
  prep<<<16384, 256, 0, stream>>>(pa);
  QKVArgs qkv = {{XQ, XK, XV}, {WTQ, WTK, WTV}, {bq, bk, bv}, {QH, KH, VT}};
  gemm_qkv<<<dim3(64, 8, 3), 256, 0, stream>>>(qkv);
  attn_fused<<<2048, 256, 0, stream>>>(QH, KH, VT, mask, attnp, OB);
  gemm_o<<<dim3(64, 8), 256, 0, stream>>>(OB, WTO, bo, outp);
}